// Round 1
// baseline (1200.914 us; speedup 1.0000x reference)
//
#include <hip/hip_runtime.h>
#include <hip/hip_bf16.h>
#include <math.h>

// StarGNN with virtual node, MI355X.
// Key simplification: NVIRT=1 virtual node is dead code for the output
// (never a src of any edge; its rows are sliced off), so we run a pure
// 2-layer GAT over the 800k real edges + fused final concat-GEMM.
//
// Softmax is computed max-free (values are O(1); softmax is shift-invariant)
// and normalization is applied once per node in the epilogue instead of
// per-edge (mathematically identical).

#define NF_IN 256
#define NF_H1 128   // H1*HID = 2*64
#define NF_OUT 128

// ---------------- Layer-1 GEMM: h = x @ W1, fused es1/ed1 ----------------
// 8 rows per block, 128 threads (thread j owns output column j).
__global__ __launch_bounds__(128) void gemm1_kernel(
    const float* __restrict__ x, const float* __restrict__ W1,
    const float* __restrict__ a1s, const float* __restrict__ a1d,
    float* __restrict__ h_a, float* __restrict__ es1, float* __restrict__ ed1,
    int N)
{
    __shared__ float4 xs[8][64];   // 8 rows x 256 floats
    const int t = threadIdx.x;
    const int base = blockIdx.x * 8;
    const float4* x4 = (const float4*)x;
    for (int idx = t; idx < 8 * 64; idx += 128) {
        int r = idx >> 6, kk = idx & 63;
        int row = base + r;
        xs[r][kk] = (row < N) ? x4[(size_t)row * 64 + kk] : make_float4(0.f, 0.f, 0.f, 0.f);
    }
    __syncthreads();

    float acc[8] = {0.f, 0.f, 0.f, 0.f, 0.f, 0.f, 0.f, 0.f};
    const int j = t;
    for (int k4 = 0; k4 < 64; ++k4) {
        const int k = k4 * 4;
        float w0 = W1[(k + 0) * 128 + j];
        float w1 = W1[(k + 1) * 128 + j];
        float w2 = W1[(k + 2) * 128 + j];
        float w3 = W1[(k + 3) * 128 + j];
#pragma unroll
        for (int r = 0; r < 8; ++r) {
            float4 xv = xs[r][k4];
            acc[r] = fmaf(xv.x, w0, acc[r]);
            acc[r] = fmaf(xv.y, w1, acc[r]);
            acc[r] = fmaf(xv.z, w2, acc[r]);
            acc[r] = fmaf(xv.w, w3, acc[r]);
        }
    }

    const float as = a1s[j];   // a1_src flat (2,64) == col index j
    const float ad = a1d[j];
    const int head = j >> 6;
    const int lane = j & 63;
#pragma unroll
    for (int r = 0; r < 8; ++r) {
        int row = base + r;
        if (row < N) h_a[(size_t)row * 128 + j] = acc[r];
        float es = acc[r] * as;
        float ed = acc[r] * ad;
#pragma unroll
        for (int off = 32; off > 0; off >>= 1) {
            es += __shfl_xor(es, off, 64);
            ed += __shfl_xor(ed, off, 64);
        }
        if (row < N && lane == 0) {
            es1[row * 2 + head] = es;
            ed1[row * 2 + head] = ed;
        }
    }
}

// ---------------- Edge pass layer 1 (H=2, C=64) ----------------
__global__ __launch_bounds__(256) void edge1_kernel(
    const int* __restrict__ src, const int* __restrict__ dst,
    const float* __restrict__ es1, const float* __restrict__ ed1,
    const float* __restrict__ h_a,
    float* __restrict__ out1, float* __restrict__ den1, int E)
{
    int gid = blockIdx.x * 256 + threadIdx.x;
    int e = gid >> 7;
    if (e >= E) return;
    int c = gid & 127;
    int s = src[e];
    int d = dst[e];
    int head = c >> 6;
    float ev = es1[s * 2 + head] + ed1[d * 2 + head];
    ev = ev > 0.f ? ev : 0.2f * ev;       // leaky_relu(0.2)
    float w = expf(ev);
    atomicAdd(&out1[(size_t)d * 128 + c], w * h_a[(size_t)s * 128 + c]);
    if ((c & 63) == 0) atomicAdd(&den1[d * 2 + head], w);
}

// ---------------- Epilogue layer 1: normalize + bias + ELU (in place) ----------------
__global__ __launch_bounds__(256) void epi1_kernel(
    float* __restrict__ h1, const float* __restrict__ den1,
    const float* __restrict__ b1, int N)
{
    int i = blockIdx.x * 256 + threadIdx.x;
    if (i >= N * 128) return;
    int n = i >> 7, c = i & 127;
    float den = den1[n * 2 + (c >> 6)];
    float v = den > 0.f ? h1[i] / den : 0.f;
    v += b1[c];
    h1[i] = v > 0.f ? v : expm1f(v);      // ELU(alpha=1)
}

// ---------------- Layer-2 GEMM: h_b = h1 @ W2, fused es2/ed2 (H=1) ----------------
__global__ __launch_bounds__(128) void gemm2_kernel(
    const float* __restrict__ h1, const float* __restrict__ W2,
    const float* __restrict__ a2s, const float* __restrict__ a2d,
    float* __restrict__ h_b, float* __restrict__ es2, float* __restrict__ ed2,
    int N)
{
    __shared__ float4 xs[8][32];   // 8 rows x 128 floats
    __shared__ float red[2][8][2];
    const int t = threadIdx.x;
    const int base = blockIdx.x * 8;
    const float4* x4 = (const float4*)h1;
    for (int idx = t; idx < 8 * 32; idx += 128) {
        int r = idx >> 5, kk = idx & 31;
        int row = base + r;
        xs[r][kk] = (row < N) ? x4[(size_t)row * 32 + kk] : make_float4(0.f, 0.f, 0.f, 0.f);
    }
    __syncthreads();

    float acc[8] = {0.f, 0.f, 0.f, 0.f, 0.f, 0.f, 0.f, 0.f};
    const int j = t;
    for (int k4 = 0; k4 < 32; ++k4) {
        const int k = k4 * 4;
        float w0 = W2[(k + 0) * 128 + j];
        float w1 = W2[(k + 1) * 128 + j];
        float w2 = W2[(k + 2) * 128 + j];
        float w3 = W2[(k + 3) * 128 + j];
#pragma unroll
        for (int r = 0; r < 8; ++r) {
            float4 xv = xs[r][k4];
            acc[r] = fmaf(xv.x, w0, acc[r]);
            acc[r] = fmaf(xv.y, w1, acc[r]);
            acc[r] = fmaf(xv.z, w2, acc[r]);
            acc[r] = fmaf(xv.w, w3, acc[r]);
        }
    }

    const float as = a2s[j];
    const float ad = a2d[j];
    const int wave = j >> 6;
    const int lane = j & 63;
#pragma unroll
    for (int r = 0; r < 8; ++r) {
        int row = base + r;
        if (row < N) h_b[(size_t)row * 128 + j] = acc[r];
        float es = acc[r] * as;
        float ed = acc[r] * ad;
#pragma unroll
        for (int off = 32; off > 0; off >>= 1) {
            es += __shfl_xor(es, off, 64);
            ed += __shfl_xor(ed, off, 64);
        }
        if (lane == 0) {
            red[wave][r][0] = es;
            red[wave][r][1] = ed;
        }
    }
    __syncthreads();
    if (t < 16) {
        int r = t >> 1, which = t & 1;
        int row = base + r;
        if (row < N) {
            float v = red[0][r][which] + red[1][r][which];
            if (which == 0) es2[row] = v; else ed2[row] = v;
        }
    }
}

// ---------------- Edge pass layer 2 (H=1, C=128) ----------------
__global__ __launch_bounds__(256) void edge2_kernel(
    const int* __restrict__ src, const int* __restrict__ dst,
    const float* __restrict__ es2, const float* __restrict__ ed2,
    const float* __restrict__ h_b,
    float* __restrict__ out2, float* __restrict__ den2, int E)
{
    int gid = blockIdx.x * 256 + threadIdx.x;
    int e = gid >> 7;
    if (e >= E) return;
    int c = gid & 127;
    int s = src[e];
    int d = dst[e];
    float ev = es2[s] + ed2[d];
    ev = ev > 0.f ? ev : 0.2f * ev;
    float w = expf(ev);
    atomicAdd(&out2[(size_t)d * 128 + c], w * h_b[(size_t)s * 128 + c]);
    if (c == 0) atomicAdd(&den2[d], w);
}

// ---------------- Final: out = [x | h1 | h2] @ Wj + bj ----------------
__global__ __launch_bounds__(128) void final_kernel(
    const float* __restrict__ x, const float* __restrict__ h1,
    const float* __restrict__ out2, const float* __restrict__ den2,
    const float* __restrict__ b2, const float* __restrict__ Wj,
    const float* __restrict__ bj, float* __restrict__ out, int N)
{
    __shared__ float xs[8][512];   // 8 rows x 512 (comb) = 16 KiB
    const int t = threadIdx.x;
    const int base = blockIdx.x * 8;
#pragma unroll
    for (int r = 0; r < 8; ++r) {
        int row = base + r;
        bool v = row < N;
        float dn = v ? den2[row] : 0.f;
        float inv = dn > 0.f ? 1.f / dn : 0.f;
        xs[r][t]       = v ? x[(size_t)row * 256 + t] : 0.f;
        xs[r][128 + t] = v ? x[(size_t)row * 256 + 128 + t] : 0.f;
        xs[r][256 + t] = v ? h1[(size_t)row * 128 + t] : 0.f;
        xs[r][384 + t] = v ? out2[(size_t)row * 128 + t] * inv + b2[t] : 0.f;
    }
    __syncthreads();

    float acc[8] = {0.f, 0.f, 0.f, 0.f, 0.f, 0.f, 0.f, 0.f};
    for (int k4 = 0; k4 < 128; ++k4) {
        const int k = k4 * 4;
        float w0 = Wj[(k + 0) * 128 + t];
        float w1 = Wj[(k + 1) * 128 + t];
        float w2 = Wj[(k + 2) * 128 + t];
        float w3 = Wj[(k + 3) * 128 + t];
#pragma unroll
        for (int r = 0; r < 8; ++r) {
            float4 xv = *(const float4*)&xs[r][k];
            acc[r] = fmaf(xv.x, w0, acc[r]);
            acc[r] = fmaf(xv.y, w1, acc[r]);
            acc[r] = fmaf(xv.z, w2, acc[r]);
            acc[r] = fmaf(xv.w, w3, acc[r]);
        }
    }
    float bb = bj[t];
#pragma unroll
    for (int r = 0; r < 8; ++r) {
        int row = base + r;
        if (row < N) out[(size_t)row * 128 + t] = acc[r] + bb;
    }
}

extern "C" void kernel_launch(void* const* d_in, const int* in_sizes, int n_in,
                              void* d_out, int out_size, void* d_ws, size_t ws_size,
                              hipStream_t stream)
{
    const float* x   = (const float*)d_in[0];      // (N, 256)
    const int*   ei  = (const int*)d_in[1];        // (2, E)
    const float* W1  = (const float*)d_in[4];      // (256, 128)
    const float* a1s = (const float*)d_in[5];      // (2, 64)
    const float* a1d = (const float*)d_in[6];
    const float* b1  = (const float*)d_in[7];      // (128,)
    const float* W2  = (const float*)d_in[8];      // (128, 128)
    const float* a2s = (const float*)d_in[9];      // (1, 128)
    const float* a2d = (const float*)d_in[10];
    const float* b2  = (const float*)d_in[11];     // (128,)
    const float* Wj  = (const float*)d_in[12];     // (512, 128)
    const float* bj  = (const float*)d_in[13];     // (128,)
    float* out = (float*)d_out;

    const int N = in_sizes[0] / NF_IN;
    const int E = in_sizes[1] / 2;
    const int* src = ei;
    const int* dst = ei + E;

    // workspace layout (floats)
    float* ws = (float*)d_ws;
    size_t nb = (size_t)N * 128;
    float* h_a  = ws;                 // layer1 h, later reused as layer2 h_b
    float* h1   = ws + nb;            // out1 accumulator, then h1 in place
    float* out2 = ws + 2 * nb;        // layer2 accumulator
    float* es1  = ws + 3 * nb;        // (N,2)
    float* ed1  = es1 + 2 * (size_t)N;
    float* es2  = ed1 + 2 * (size_t)N; // (N,)
    float* ed2  = es2 + (size_t)N;
    float* den1 = ed2 + (size_t)N;    // (N,2)
    float* den2 = den1 + 2 * (size_t)N;

    // zero accumulators (out1+out2 contiguous; den1+den2 contiguous)
    hipMemsetAsync(h1, 0, 2 * nb * sizeof(float), stream);
    hipMemsetAsync(den1, 0, 3 * (size_t)N * sizeof(float), stream);

    const int rowBlocks = (N + 7) / 8;
    const int edgeBlocks = (E * 128 + 255) / 256;
    const int epiBlocks = (N * 128 + 255) / 256;

    gemm1_kernel<<<rowBlocks, 128, 0, stream>>>(x, W1, a1s, a1d, h_a, es1, ed1, N);
    edge1_kernel<<<edgeBlocks, 256, 0, stream>>>(src, dst, es1, ed1, h_a, h1, den1, E);
    epi1_kernel<<<epiBlocks, 256, 0, stream>>>(h1, den1, b1, N);
    gemm2_kernel<<<rowBlocks, 128, 0, stream>>>(h1, W2, a2s, a2d, h_a, es2, ed2, N);
    edge2_kernel<<<edgeBlocks, 256, 0, stream>>>(src, dst, es2, ed2, h_a, out2, den2, E);
    final_kernel<<<rowBlocks, 128, 0, stream>>>(x, h1, out2, den2, b2, Wj, bj, out, N);
}

// Round 9
// 646.565 us; speedup vs baseline: 1.8574x; 1.8574x over previous
//
#include <hip/hip_runtime.h>
#include <hip/hip_bf16.h>
#include <math.h>

// StarGNN with virtual node, MI355X.
// R1 (resubmitted R8 — rounds 1-7 hit GPUAcquisitionTimeout, no data):
// replace atomic scatter edge passes (atomic-RMW bound, 450MB WRITE_SIZE,
// 424us each) with CSR-by-dst build + per-node register gather. One wave per
// node, lane owns 2 channels (float2). Attention weight w is uniform across
// each head's lanes -> denominator tracked per-lane with no reduction.
// Normalize+bias+activation fused into the gather epilogue.
//
// NVIRT=1 virtual node is dead code for the output (never a src; rows sliced
// off) -> pure 2-layer GAT over the 800k real edges + fused concat-GEMM.
// Softmax is max-free (shift-invariant; values are O(1)).

#define NF_IN 256

// ---------------- CSR build ----------------
__global__ __launch_bounds__(256) void hist_kernel(
    const int* __restrict__ dst, int* __restrict__ deg, int E)
{
    int e = blockIdx.x * 256 + threadIdx.x;
    if (e < E) atomicAdd(&deg[dst[e]], 1);
}

// per-256-chunk sums
__global__ __launch_bounds__(256) void scan_partial(
    const int* __restrict__ deg, int* __restrict__ bsum, int N)
{
    __shared__ int sm[256];
    int i = blockIdx.x * 256 + threadIdx.x;
    int v = (i < N) ? deg[i] : 0;
    sm[threadIdx.x] = v;
    __syncthreads();
    for (int off = 128; off > 0; off >>= 1) {
        if (threadIdx.x < off) sm[threadIdx.x] += sm[threadIdx.x + off];
        __syncthreads();
    }
    if (threadIdx.x == 0) bsum[blockIdx.x] = sm[0];
}

// exclusive scan of block sums (nb <= 1024)
__global__ __launch_bounds__(1024) void scan_bsum(
    int* __restrict__ bsum, int nb, int* __restrict__ rowptr, int N, int E)
{
    __shared__ int sm[1024];
    int t = threadIdx.x;
    int v = (t < nb) ? bsum[t] : 0;
    sm[t] = v;
    __syncthreads();
    for (int off = 1; off < 1024; off <<= 1) {
        int x = (t >= off) ? sm[t - off] : 0;
        __syncthreads();
        sm[t] += x;
        __syncthreads();
    }
    if (t < nb) bsum[t] = sm[t] - v;   // exclusive
    if (t == 0) rowptr[N] = E;
}

// in-chunk exclusive scan + block offset -> rowptr
__global__ __launch_bounds__(256) void scan_final(
    const int* __restrict__ deg, const int* __restrict__ bsum,
    int* __restrict__ rowptr, int N)
{
    __shared__ int sm[256];
    int t = threadIdx.x;
    int i = blockIdx.x * 256 + t;
    int v = (i < N) ? deg[i] : 0;
    sm[t] = v;
    __syncthreads();
    for (int off = 1; off < 256; off <<= 1) {
        int x = (t >= off) ? sm[t - off] : 0;
        __syncthreads();
        sm[t] += x;
        __syncthreads();
    }
    if (i < N) rowptr[i] = sm[t] - v + bsum[blockIdx.x];
}

__global__ __launch_bounds__(256) void fill_kernel(
    const int* __restrict__ src, const int* __restrict__ dst,
    const int* __restrict__ rowptr, int* __restrict__ cur,
    int* __restrict__ csr_src, int E)
{
    int e = blockIdx.x * 256 + threadIdx.x;
    if (e >= E) return;
    int d = dst[e];
    int pos = rowptr[d] + atomicAdd(&cur[d], 1);
    csr_src[pos] = src[e];
}

// ---------------- Layer-1 GEMM: h = x @ W1, fused es1/ed1 ----------------
__global__ __launch_bounds__(128) void gemm1_kernel(
    const float* __restrict__ x, const float* __restrict__ W1,
    const float* __restrict__ a1s, const float* __restrict__ a1d,
    float* __restrict__ h_a, float* __restrict__ es1, float* __restrict__ ed1,
    int N)
{
    __shared__ float4 xs[8][64];   // 8 rows x 256 floats
    const int t = threadIdx.x;
    const int base = blockIdx.x * 8;
    const float4* x4 = (const float4*)x;
    for (int idx = t; idx < 8 * 64; idx += 128) {
        int r = idx >> 6, kk = idx & 63;
        int row = base + r;
        xs[r][kk] = (row < N) ? x4[(size_t)row * 64 + kk] : make_float4(0.f, 0.f, 0.f, 0.f);
    }
    __syncthreads();

    float acc[8] = {0.f, 0.f, 0.f, 0.f, 0.f, 0.f, 0.f, 0.f};
    const int j = t;
    for (int k4 = 0; k4 < 64; ++k4) {
        const int k = k4 * 4;
        float w0 = W1[(k + 0) * 128 + j];
        float w1 = W1[(k + 1) * 128 + j];
        float w2 = W1[(k + 2) * 128 + j];
        float w3 = W1[(k + 3) * 128 + j];
#pragma unroll
        for (int r = 0; r < 8; ++r) {
            float4 xv = xs[r][k4];
            acc[r] = fmaf(xv.x, w0, acc[r]);
            acc[r] = fmaf(xv.y, w1, acc[r]);
            acc[r] = fmaf(xv.z, w2, acc[r]);
            acc[r] = fmaf(xv.w, w3, acc[r]);
        }
    }

    const float as = a1s[j];
    const float ad = a1d[j];
    const int head = j >> 6;
    const int lane = j & 63;
#pragma unroll
    for (int r = 0; r < 8; ++r) {
        int row = base + r;
        if (row < N) h_a[(size_t)row * 128 + j] = acc[r];
        float es = acc[r] * as;
        float ed = acc[r] * ad;
#pragma unroll
        for (int off = 32; off > 0; off >>= 1) {
            es += __shfl_xor(es, off, 64);
            ed += __shfl_xor(ed, off, 64);
        }
        if (row < N && lane == 0) {
            es1[row * 2 + head] = es;
            ed1[row * 2 + head] = ed;
        }
    }
}

// ---------------- Gather layer 1 (H=2, C=64) ----------------
// One wave per node; lane owns channels {2*lane, 2*lane+1}; head = lane>>5.
// w uniform across each head's 32 lanes -> den tracked per-lane, no reduce.
// Fused: normalize + b1 + ELU.
__global__ __launch_bounds__(256) void gather1_kernel(
    const int* __restrict__ rowptr, const int* __restrict__ csr_src,
    const float* __restrict__ es1, const float* __restrict__ ed1,
    const float* __restrict__ h_a, const float* __restrict__ b1,
    float* __restrict__ h1, int N)
{
    int node = blockIdx.x * 4 + (threadIdx.x >> 6);
    if (node >= N) return;
    int lane = threadIdx.x & 63;
    int head = lane >> 5;
    float edh = ed1[node * 2 + head];
    int b = rowptr[node], e = rowptr[node + 1];
    float acc0 = 0.f, acc1 = 0.f, den = 0.f;
    int s = (b < e) ? csr_src[b] : 0;
    for (int i = b; i < e; ++i) {
        int snext = (i + 1 < e) ? csr_src[i + 1] : 0;
        float ev = es1[s * 2 + head] + edh;
        ev = ev > 0.f ? ev : 0.2f * ev;         // leaky_relu(0.2)
        float w = expf(ev);
        float2 hv = *(const float2*)&h_a[(size_t)s * 128 + lane * 2];
        acc0 = fmaf(w, hv.x, acc0);
        acc1 = fmaf(w, hv.y, acc1);
        den += w;
        s = snext;
    }
    float inv = den > 0.f ? 1.f / den : 0.f;
    float2 bb = *(const float2*)&b1[lane * 2];
    float v0 = acc0 * inv + bb.x;
    float v1 = acc1 * inv + bb.y;
    v0 = v0 > 0.f ? v0 : expm1f(v0);            // ELU
    v1 = v1 > 0.f ? v1 : expm1f(v1);
    *(float2*)&h1[(size_t)node * 128 + lane * 2] = make_float2(v0, v1);
}

// ---------------- Layer-2 GEMM: h_b = h1 @ W2, fused es2/ed2 (H=1) ----------------
__global__ __launch_bounds__(128) void gemm2_kernel(
    const float* __restrict__ h1, const float* __restrict__ W2,
    const float* __restrict__ a2s, const float* __restrict__ a2d,
    float* __restrict__ h_b, float* __restrict__ es2, float* __restrict__ ed2,
    int N)
{
    __shared__ float4 xs[8][32];   // 8 rows x 128 floats
    __shared__ float red[2][8][2];
    const int t = threadIdx.x;
    const int base = blockIdx.x * 8;
    const float4* x4 = (const float4*)h1;
    for (int idx = t; idx < 8 * 32; idx += 128) {
        int r = idx >> 5, kk = idx & 31;
        int row = base + r;
        xs[r][kk] = (row < N) ? x4[(size_t)row * 32 + kk] : make_float4(0.f, 0.f, 0.f, 0.f);
    }
    __syncthreads();

    float acc[8] = {0.f, 0.f, 0.f, 0.f, 0.f, 0.f, 0.f, 0.f};
    const int j = t;
    for (int k4 = 0; k4 < 32; ++k4) {
        const int k = k4 * 4;
        float w0 = W2[(k + 0) * 128 + j];
        float w1 = W2[(k + 1) * 128 + j];
        float w2 = W2[(k + 2) * 128 + j];
        float w3 = W2[(k + 3) * 128 + j];
#pragma unroll
        for (int r = 0; r < 8; ++r) {
            float4 xv = xs[r][k4];
            acc[r] = fmaf(xv.x, w0, acc[r]);
            acc[r] = fmaf(xv.y, w1, acc[r]);
            acc[r] = fmaf(xv.z, w2, acc[r]);
            acc[r] = fmaf(xv.w, w3, acc[r]);
        }
    }

    const float as = a2s[j];
    const float ad = a2d[j];
    const int wave = j >> 6;
    const int lane = j & 63;
#pragma unroll
    for (int r = 0; r < 8; ++r) {
        int row = base + r;
        if (row < N) h_b[(size_t)row * 128 + j] = acc[r];
        float es = acc[r] * as;
        float ed = acc[r] * ad;
#pragma unroll
        for (int off = 32; off > 0; off >>= 1) {
            es += __shfl_xor(es, off, 64);
            ed += __shfl_xor(ed, off, 64);
        }
        if (lane == 0) {
            red[wave][r][0] = es;
            red[wave][r][1] = ed;
        }
    }
    __syncthreads();
    if (t < 16) {
        int r = t >> 1, which = t & 1;
        int row = base + r;
        if (row < N) {
            float v = red[0][r][which] + red[1][r][which];
            if (which == 0) es2[row] = v; else ed2[row] = v;
        }
    }
}

// ---------------- Gather layer 2 (H=1, C=128) ----------------
// Fused: normalize + b2 (no activation). Output ready for final concat.
__global__ __launch_bounds__(256) void gather2_kernel(
    const int* __restrict__ rowptr, const int* __restrict__ csr_src,
    const float* __restrict__ es2, const float* __restrict__ ed2,
    const float* __restrict__ h_b, const float* __restrict__ b2,
    float* __restrict__ h2n, int N)
{
    int node = blockIdx.x * 4 + (threadIdx.x >> 6);
    if (node >= N) return;
    int lane = threadIdx.x & 63;
    float edh = ed2[node];
    int b = rowptr[node], e = rowptr[node + 1];
    float acc0 = 0.f, acc1 = 0.f, den = 0.f;
    int s = (b < e) ? csr_src[b] : 0;
    for (int i = b; i < e; ++i) {
        int snext = (i + 1 < e) ? csr_src[i + 1] : 0;
        float ev = es2[s] + edh;
        ev = ev > 0.f ? ev : 0.2f * ev;
        float w = expf(ev);
        float2 hv = *(const float2*)&h_b[(size_t)s * 128 + lane * 2];
        acc0 = fmaf(w, hv.x, acc0);
        acc1 = fmaf(w, hv.y, acc1);
        den += w;
        s = snext;
    }
    float inv = den > 0.f ? 1.f / den : 0.f;
    float2 bb = *(const float2*)&b2[lane * 2];
    *(float2*)&h2n[(size_t)node * 128 + lane * 2] =
        make_float2(acc0 * inv + bb.x, acc1 * inv + bb.y);
}

// ---------------- Final: out = [x | h1 | h2n] @ Wj + bj ----------------
__global__ __launch_bounds__(128) void final_kernel(
    const float* __restrict__ x, const float* __restrict__ h1,
    const float* __restrict__ h2n, const float* __restrict__ Wj,
    const float* __restrict__ bj, float* __restrict__ out, int N)
{
    __shared__ float xs[8][512];   // 8 rows x 512 (comb) = 16 KiB
    const int t = threadIdx.x;
    const int base = blockIdx.x * 8;
#pragma unroll
    for (int r = 0; r < 8; ++r) {
        int row = base + r;
        bool v = row < N;
        xs[r][t]       = v ? x[(size_t)row * 256 + t] : 0.f;
        xs[r][128 + t] = v ? x[(size_t)row * 256 + 128 + t] : 0.f;
        xs[r][256 + t] = v ? h1[(size_t)row * 128 + t] : 0.f;
        xs[r][384 + t] = v ? h2n[(size_t)row * 128 + t] : 0.f;
    }
    __syncthreads();

    float acc[8] = {0.f, 0.f, 0.f, 0.f, 0.f, 0.f, 0.f, 0.f};
    for (int k4 = 0; k4 < 128; ++k4) {
        const int k = k4 * 4;
        float w0 = Wj[(k + 0) * 128 + t];
        float w1 = Wj[(k + 1) * 128 + t];
        float w2 = Wj[(k + 2) * 128 + t];
        float w3 = Wj[(k + 3) * 128 + t];
#pragma unroll
        for (int r = 0; r < 8; ++r) {
            float4 xv = *(const float4*)&xs[r][k];
            acc[r] = fmaf(xv.x, w0, acc[r]);
            acc[r] = fmaf(xv.y, w1, acc[r]);
            acc[r] = fmaf(xv.z, w2, acc[r]);
            acc[r] = fmaf(xv.w, w3, acc[r]);
        }
    }
    float bb = bj[t];
#pragma unroll
    for (int r = 0; r < 8; ++r) {
        int row = base + r;
        if (row < N) out[(size_t)row * 128 + t] = acc[r] + bb;
    }
}

extern "C" void kernel_launch(void* const* d_in, const int* in_sizes, int n_in,
                              void* d_out, int out_size, void* d_ws, size_t ws_size,
                              hipStream_t stream)
{
    const float* x   = (const float*)d_in[0];      // (N, 256)
    const int*   ei  = (const int*)d_in[1];        // (2, E)
    const float* W1  = (const float*)d_in[4];      // (256, 128)
    const float* a1s = (const float*)d_in[5];      // (2, 64)
    const float* a1d = (const float*)d_in[6];
    const float* b1  = (const float*)d_in[7];      // (128,)
    const float* W2  = (const float*)d_in[8];      // (128, 128)
    const float* a2s = (const float*)d_in[9];      // (1, 128)
    const float* a2d = (const float*)d_in[10];
    const float* b2  = (const float*)d_in[11];     // (128,)
    const float* Wj  = (const float*)d_in[12];     // (512, 128)
    const float* bj  = (const float*)d_in[13];     // (128,)
    float* out = (float*)d_out;

    const int N = in_sizes[0] / NF_IN;
    const int E = in_sizes[1] / 2;
    const int* src = ei;
    const int* dst = ei + E;

    // ---- workspace layout ----
    char* wp = (char*)d_ws;
    size_t nb = (size_t)N * 128;
    float* h_a  = (float*)wp; wp += nb * sizeof(float);   // h (layer1), reused as h_b (layer2)
    float* h1   = (float*)wp; wp += nb * sizeof(float);
    float* h2n  = (float*)wp; wp += nb * sizeof(float);
    float* es1  = (float*)wp; wp += 2 * (size_t)N * sizeof(float);
    float* ed1  = (float*)wp; wp += 2 * (size_t)N * sizeof(float);
    float* es2  = (float*)wp; wp += (size_t)N * sizeof(float);
    float* ed2  = (float*)wp; wp += (size_t)N * sizeof(float);
    int* deg    = (int*)wp;   wp += (size_t)N * sizeof(int);   // deg + cur contiguous for one memset
    int* cur    = (int*)wp;   wp += (size_t)N * sizeof(int);
    int* rowptr = (int*)wp;   wp += ((size_t)N + 1) * sizeof(int);
    int* bsum   = (int*)wp;   wp += 1024 * sizeof(int);
    int* csr_src= (int*)wp;   wp += (size_t)E * sizeof(int);

    const int NB = (N + 255) / 256;            // 196 (<=1024 supported by scan_bsum)
    const int edgeBlocks = (E + 255) / 256;
    const int rowBlocks = (N + 7) / 8;
    const int nodeBlocks = (N + 3) / 4;

    // CSR build (graph shared by both layers)
    hipMemsetAsync(deg, 0, 2 * (size_t)N * sizeof(int), stream);
    hist_kernel<<<edgeBlocks, 256, 0, stream>>>(dst, deg, E);
    scan_partial<<<NB, 256, 0, stream>>>(deg, bsum, N);
    scan_bsum<<<1, 1024, 0, stream>>>(bsum, NB, rowptr, N, E);
    scan_final<<<NB, 256, 0, stream>>>(deg, bsum, rowptr, N);
    fill_kernel<<<edgeBlocks, 256, 0, stream>>>(src, dst, rowptr, cur, csr_src, E);

    // layer 1
    gemm1_kernel<<<rowBlocks, 128, 0, stream>>>(x, W1, a1s, a1d, h_a, es1, ed1, N);
    gather1_kernel<<<nodeBlocks, 256, 0, stream>>>(rowptr, csr_src, es1, ed1, h_a, b1, h1, N);
    // layer 2
    gemm2_kernel<<<rowBlocks, 128, 0, stream>>>(h1, W2, a2s, a2d, h_a, es2, ed2, N);
    gather2_kernel<<<nodeBlocks, 256, 0, stream>>>(rowptr, csr_src, es2, ed2, h_a, b2, h2n, N);
    // final fused concat-GEMM
    final_kernel<<<rowBlocks, 128, 0, stream>>>(x, h1, h2n, Wj, bj, out, N);
}

// Round 11
// 604.186 us; speedup vs baseline: 1.9877x; 1.0701x over previous
//
#include <hip/hip_runtime.h>
#include <hip/hip_bf16.h>
#include <math.h>

// StarGNN with virtual node, MI355X.
// R9 (resubmitted R10 — R9's bench hit GPUAcquisitionTimeout):
// R1's CSR-gather confirmed (1200 -> 646us; scatter atomics gone).
// final_kernel was top dispatch (160us, VALUBusy 76%, MfmaUtil 0, HBM 6%,
// 26% of fp32 peak) -> rewritten as LDS-tiled GEMM: 64x128 block tile,
// k-step 64, 256 threads, 8x4 register tile/thread, A transposed in LDS,
// Wj staged cooperatively (L2 traffic for Wj drops 8x). Accumulation order
// over k unchanged -> numerics identical. Everything else untouched.
//
// NVIRT=1 virtual node is dead code for the output -> pure 2-layer GAT over
// the 800k real edges + fused concat-GEMM. Softmax max-free (shift-invariant).

#define NF_IN 256

// ---------------- CSR build ----------------
__global__ __launch_bounds__(256) void hist_kernel(
    const int* __restrict__ dst, int* __restrict__ deg, int E)
{
    int e = blockIdx.x * 256 + threadIdx.x;
    if (e < E) atomicAdd(&deg[dst[e]], 1);
}

__global__ __launch_bounds__(256) void scan_partial(
    const int* __restrict__ deg, int* __restrict__ bsum, int N)
{
    __shared__ int sm[256];
    int i = blockIdx.x * 256 + threadIdx.x;
    int v = (i < N) ? deg[i] : 0;
    sm[threadIdx.x] = v;
    __syncthreads();
    for (int off = 128; off > 0; off >>= 1) {
        if (threadIdx.x < off) sm[threadIdx.x] += sm[threadIdx.x + off];
        __syncthreads();
    }
    if (threadIdx.x == 0) bsum[blockIdx.x] = sm[0];
}

__global__ __launch_bounds__(1024) void scan_bsum(
    int* __restrict__ bsum, int nb, int* __restrict__ rowptr, int N, int E)
{
    __shared__ int sm[1024];
    int t = threadIdx.x;
    int v = (t < nb) ? bsum[t] : 0;
    sm[t] = v;
    __syncthreads();
    for (int off = 1; off < 1024; off <<= 1) {
        int x = (t >= off) ? sm[t - off] : 0;
        __syncthreads();
        sm[t] += x;
        __syncthreads();
    }
    if (t < nb) bsum[t] = sm[t] - v;   // exclusive
    if (t == 0) rowptr[N] = E;
}

__global__ __launch_bounds__(256) void scan_final(
    const int* __restrict__ deg, const int* __restrict__ bsum,
    int* __restrict__ rowptr, int N)
{
    __shared__ int sm[256];
    int t = threadIdx.x;
    int i = blockIdx.x * 256 + t;
    int v = (i < N) ? deg[i] : 0;
    sm[t] = v;
    __syncthreads();
    for (int off = 1; off < 256; off <<= 1) {
        int x = (t >= off) ? sm[t - off] : 0;
        __syncthreads();
        sm[t] += x;
        __syncthreads();
    }
    if (i < N) rowptr[i] = sm[t] - v + bsum[blockIdx.x];
}

__global__ __launch_bounds__(256) void fill_kernel(
    const int* __restrict__ src, const int* __restrict__ dst,
    const int* __restrict__ rowptr, int* __restrict__ cur,
    int* __restrict__ csr_src, int E)
{
    int e = blockIdx.x * 256 + threadIdx.x;
    if (e >= E) return;
    int d = dst[e];
    int pos = rowptr[d] + atomicAdd(&cur[d], 1);
    csr_src[pos] = src[e];
}

// ---------------- Layer-1 GEMM: h = x @ W1, fused es1/ed1 ----------------
__global__ __launch_bounds__(128) void gemm1_kernel(
    const float* __restrict__ x, const float* __restrict__ W1,
    const float* __restrict__ a1s, const float* __restrict__ a1d,
    float* __restrict__ h_a, float* __restrict__ es1, float* __restrict__ ed1,
    int N)
{
    __shared__ float4 xs[8][64];   // 8 rows x 256 floats
    const int t = threadIdx.x;
    const int base = blockIdx.x * 8;
    const float4* x4 = (const float4*)x;
    for (int idx = t; idx < 8 * 64; idx += 128) {
        int r = idx >> 6, kk = idx & 63;
        int row = base + r;
        xs[r][kk] = (row < N) ? x4[(size_t)row * 64 + kk] : make_float4(0.f, 0.f, 0.f, 0.f);
    }
    __syncthreads();

    float acc[8] = {0.f, 0.f, 0.f, 0.f, 0.f, 0.f, 0.f, 0.f};
    const int j = t;
    for (int k4 = 0; k4 < 64; ++k4) {
        const int k = k4 * 4;
        float w0 = W1[(k + 0) * 128 + j];
        float w1 = W1[(k + 1) * 128 + j];
        float w2 = W1[(k + 2) * 128 + j];
        float w3 = W1[(k + 3) * 128 + j];
#pragma unroll
        for (int r = 0; r < 8; ++r) {
            float4 xv = xs[r][k4];
            acc[r] = fmaf(xv.x, w0, acc[r]);
            acc[r] = fmaf(xv.y, w1, acc[r]);
            acc[r] = fmaf(xv.z, w2, acc[r]);
            acc[r] = fmaf(xv.w, w3, acc[r]);
        }
    }

    const float as = a1s[j];
    const float ad = a1d[j];
    const int head = j >> 6;
    const int lane = j & 63;
#pragma unroll
    for (int r = 0; r < 8; ++r) {
        int row = base + r;
        if (row < N) h_a[(size_t)row * 128 + j] = acc[r];
        float es = acc[r] * as;
        float ed = acc[r] * ad;
#pragma unroll
        for (int off = 32; off > 0; off >>= 1) {
            es += __shfl_xor(es, off, 64);
            ed += __shfl_xor(ed, off, 64);
        }
        if (row < N && lane == 0) {
            es1[row * 2 + head] = es;
            ed1[row * 2 + head] = ed;
        }
    }
}

// ---------------- Gather layer 1 (H=2, C=64) ----------------
__global__ __launch_bounds__(256) void gather1_kernel(
    const int* __restrict__ rowptr, const int* __restrict__ csr_src,
    const float* __restrict__ es1, const float* __restrict__ ed1,
    const float* __restrict__ h_a, const float* __restrict__ b1,
    float* __restrict__ h1, int N)
{
    int node = blockIdx.x * 4 + (threadIdx.x >> 6);
    if (node >= N) return;
    int lane = threadIdx.x & 63;
    int head = lane >> 5;
    float edh = ed1[node * 2 + head];
    int b = rowptr[node], e = rowptr[node + 1];
    float acc0 = 0.f, acc1 = 0.f, den = 0.f;
    int s = (b < e) ? csr_src[b] : 0;
    for (int i = b; i < e; ++i) {
        int snext = (i + 1 < e) ? csr_src[i + 1] : 0;
        float ev = es1[s * 2 + head] + edh;
        ev = ev > 0.f ? ev : 0.2f * ev;         // leaky_relu(0.2)
        float w = expf(ev);
        float2 hv = *(const float2*)&h_a[(size_t)s * 128 + lane * 2];
        acc0 = fmaf(w, hv.x, acc0);
        acc1 = fmaf(w, hv.y, acc1);
        den += w;
        s = snext;
    }
    float inv = den > 0.f ? 1.f / den : 0.f;
    float2 bb = *(const float2*)&b1[lane * 2];
    float v0 = acc0 * inv + bb.x;
    float v1 = acc1 * inv + bb.y;
    v0 = v0 > 0.f ? v0 : expm1f(v0);            // ELU
    v1 = v1 > 0.f ? v1 : expm1f(v1);
    *(float2*)&h1[(size_t)node * 128 + lane * 2] = make_float2(v0, v1);
}

// ---------------- Layer-2 GEMM: h_b = h1 @ W2, fused es2/ed2 (H=1) ----------------
__global__ __launch_bounds__(128) void gemm2_kernel(
    const float* __restrict__ h1, const float* __restrict__ W2,
    const float* __restrict__ a2s, const float* __restrict__ a2d,
    float* __restrict__ h_b, float* __restrict__ es2, float* __restrict__ ed2,
    int N)
{
    __shared__ float4 xs[8][32];   // 8 rows x 128 floats
    __shared__ float red[2][8][2];
    const int t = threadIdx.x;
    const int base = blockIdx.x * 8;
    const float4* x4 = (const float4*)h1;
    for (int idx = t; idx < 8 * 32; idx += 128) {
        int r = idx >> 5, kk = idx & 31;
        int row = base + r;
        xs[r][kk] = (row < N) ? x4[(size_t)row * 32 + kk] : make_float4(0.f, 0.f, 0.f, 0.f);
    }
    __syncthreads();

    float acc[8] = {0.f, 0.f, 0.f, 0.f, 0.f, 0.f, 0.f, 0.f};
    const int j = t;
    for (int k4 = 0; k4 < 32; ++k4) {
        const int k = k4 * 4;
        float w0 = W2[(k + 0) * 128 + j];
        float w1 = W2[(k + 1) * 128 + j];
        float w2 = W2[(k + 2) * 128 + j];
        float w3 = W2[(k + 3) * 128 + j];
#pragma unroll
        for (int r = 0; r < 8; ++r) {
            float4 xv = xs[r][k4];
            acc[r] = fmaf(xv.x, w0, acc[r]);
            acc[r] = fmaf(xv.y, w1, acc[r]);
            acc[r] = fmaf(xv.z, w2, acc[r]);
            acc[r] = fmaf(xv.w, w3, acc[r]);
        }
    }

    const float as = a2s[j];
    const float ad = a2d[j];
    const int wave = j >> 6;
    const int lane = j & 63;
#pragma unroll
    for (int r = 0; r < 8; ++r) {
        int row = base + r;
        if (row < N) h_b[(size_t)row * 128 + j] = acc[r];
        float es = acc[r] * as;
        float ed = acc[r] * ad;
#pragma unroll
        for (int off = 32; off > 0; off >>= 1) {
            es += __shfl_xor(es, off, 64);
            ed += __shfl_xor(ed, off, 64);
        }
        if (lane == 0) {
            red[wave][r][0] = es;
            red[wave][r][1] = ed;
        }
    }
    __syncthreads();
    if (t < 16) {
        int r = t >> 1, which = t & 1;
        int row = base + r;
        if (row < N) {
            float v = red[0][r][which] + red[1][r][which];
            if (which == 0) es2[row] = v; else ed2[row] = v;
        }
    }
}

// ---------------- Gather layer 2 (H=1, C=128) ----------------
__global__ __launch_bounds__(256) void gather2_kernel(
    const int* __restrict__ rowptr, const int* __restrict__ csr_src,
    const float* __restrict__ es2, const float* __restrict__ ed2,
    const float* __restrict__ h_b, const float* __restrict__ b2,
    float* __restrict__ h2n, int N)
{
    int node = blockIdx.x * 4 + (threadIdx.x >> 6);
    if (node >= N) return;
    int lane = threadIdx.x & 63;
    float edh = ed2[node];
    int b = rowptr[node], e = rowptr[node + 1];
    float acc0 = 0.f, acc1 = 0.f, den = 0.f;
    int s = (b < e) ? csr_src[b] : 0;
    for (int i = b; i < e; ++i) {
        int snext = (i + 1 < e) ? csr_src[i + 1] : 0;
        float ev = es2[s] + edh;
        ev = ev > 0.f ? ev : 0.2f * ev;
        float w = expf(ev);
        float2 hv = *(const float2*)&h_b[(size_t)s * 128 + lane * 2];
        acc0 = fmaf(w, hv.x, acc0);
        acc1 = fmaf(w, hv.y, acc1);
        den += w;
        s = snext;
    }
    float inv = den > 0.f ? 1.f / den : 0.f;
    float2 bb = *(const float2*)&b2[lane * 2];
    *(float2*)&h2n[(size_t)node * 128 + lane * 2] =
        make_float2(acc0 * inv + bb.x, acc1 * inv + bb.y);
}

// ---------------- Final: out = [x | h1 | h2n] @ Wj + bj (LDS-tiled) ----------------
// 64-row x 128-col block tile, k-step 64, 256 threads.
// Thread (tx = t&31, ty = t>>5): 8 rows (ty*8..+7) x 4 cols (tx*4..+3).
// A staged TRANSPOSED (At[k][row]) so compute reads are float4 over rows;
// k accumulation order identical to the previous kernel -> same numerics.
__global__ __launch_bounds__(256) void final_kernel(
    const float* __restrict__ x, const float* __restrict__ h1,
    const float* __restrict__ h2n, const float* __restrict__ Wj,
    const float* __restrict__ bj, float* __restrict__ out, int N)
{
    __shared__ float At[64][64];    // 16 KiB, transposed A tile: At[k][row]
    __shared__ float Bs[64][128];   // 32 KiB, Wj tile

    const int t  = threadIdx.x;
    const int tx = t & 31;
    const int ty = t >> 5;
    const int rowbase = blockIdx.x * 64;

    float acc[8][4] = {};

    for (int k0 = 0; k0 < 512; k0 += 64) {
        // select source for this 64-aligned k slice (uniform across block)
        const float* sp; int width;
        if (k0 < 256)      { sp = x   + k0;         width = 256; }
        else if (k0 < 384) { sp = h1  + (k0 - 256); width = 128; }
        else               { sp = h2n + (k0 - 384); width = 128; }

        // ---- stage A transposed: thread handles row r = t>>2, k-chunk (t&3)*16 ----
        {
            int r  = t >> 2;            // 0..63
            int kq = (t & 3) * 16;      // 0,16,32,48
            int row = rowbase + r;
#pragma unroll
            for (int i = 0; i < 4; ++i) {
                int kl = kq + i * 4;    // local k of this float4
                float4 v = (row < N)
                    ? *(const float4*)&sp[(size_t)row * width + kl]
                    : make_float4(0.f, 0.f, 0.f, 0.f);
                At[kl + 0][r] = v.x;
                At[kl + 1][r] = v.y;
                At[kl + 2][r] = v.z;
                At[kl + 3][r] = v.w;
            }
        }
        // ---- stage B: Wj[k0..k0+63][0..127], 2048 float4, 8 per thread ----
#pragma unroll
        for (int j = 0; j < 8; ++j) {
            int idx = t + j * 256;
            int kk = idx >> 5, c4 = idx & 31;
            *(float4*)&Bs[kk][c4 * 4] =
                *(const float4*)&Wj[(size_t)(k0 + kk) * 128 + c4 * 4];
        }
        __syncthreads();

        // ---- compute: 64 k x (8x4) register tile ----
        for (int kk = 0; kk < 64; ++kk) {
            float4 b4 = *(const float4*)&Bs[kk][tx * 4];
            float4 a0 = *(const float4*)&At[kk][ty * 8];
            float4 a1 = *(const float4*)&At[kk][ty * 8 + 4];
            float a[8] = {a0.x, a0.y, a0.z, a0.w, a1.x, a1.y, a1.z, a1.w};
            float b[4] = {b4.x, b4.y, b4.z, b4.w};
#pragma unroll
            for (int r = 0; r < 8; ++r)
#pragma unroll
                for (int c = 0; c < 4; ++c)
                    acc[r][c] = fmaf(a[r], b[c], acc[r][c]);
        }
        __syncthreads();
    }

    float4 bb = *(const float4*)&bj[tx * 4];
#pragma unroll
    for (int r = 0; r < 8; ++r) {
        int row = rowbase + ty * 8 + r;
        if (row < N) {
            float4 o = make_float4(acc[r][0] + bb.x, acc[r][1] + bb.y,
                                   acc[r][2] + bb.z, acc[r][3] + bb.w);
            *(float4*)&out[(size_t)row * 128 + tx * 4] = o;
        }
    }
}

extern "C" void kernel_launch(void* const* d_in, const int* in_sizes, int n_in,
                              void* d_out, int out_size, void* d_ws, size_t ws_size,
                              hipStream_t stream)
{
    const float* x   = (const float*)d_in[0];      // (N, 256)
    const int*   ei  = (const int*)d_in[1];        // (2, E)
    const float* W1  = (const float*)d_in[4];      // (256, 128)
    const float* a1s = (const float*)d_in[5];      // (2, 64)
    const float* a1d = (const float*)d_in[6];
    const float* b1  = (const float*)d_in[7];      // (128,)
    const float* W2  = (const float*)d_in[8];      // (128, 128)
    const float* a2s = (const float*)d_in[9];      // (1, 128)
    const float* a2d = (const float*)d_in[10];
    const float* b2  = (const float*)d_in[11];     // (128,)
    const float* Wj  = (const float*)d_in[12];     // (512, 128)
    const float* bj  = (const float*)d_in[13];     // (128,)
    float* out = (float*)d_out;

    const int N = in_sizes[0] / NF_IN;
    const int E = in_sizes[1] / 2;
    const int* src = ei;
    const int* dst = ei + E;

    // ---- workspace layout ----
    char* wp = (char*)d_ws;
    size_t nb = (size_t)N * 128;
    float* h_a  = (float*)wp; wp += nb * sizeof(float);   // h (layer1), reused as h_b (layer2)
    float* h1   = (float*)wp; wp += nb * sizeof(float);
    float* h2n  = (float*)wp; wp += nb * sizeof(float);
    float* es1  = (float*)wp; wp += 2 * (size_t)N * sizeof(float);
    float* ed1  = (float*)wp; wp += 2 * (size_t)N * sizeof(float);
    float* es2  = (float*)wp; wp += (size_t)N * sizeof(float);
    float* ed2  = (float*)wp; wp += (size_t)N * sizeof(float);
    int* deg    = (int*)wp;   wp += (size_t)N * sizeof(int);   // deg + cur contiguous for one memset
    int* cur    = (int*)wp;   wp += (size_t)N * sizeof(int);
    int* rowptr = (int*)wp;   wp += ((size_t)N + 1) * sizeof(int);
    int* bsum   = (int*)wp;   wp += 1024 * sizeof(int);
    int* csr_src= (int*)wp;   wp += (size_t)E * sizeof(int);

    const int NB = (N + 255) / 256;            // 196 (<=1024 supported by scan_bsum)
    const int edgeBlocks = (E + 255) / 256;
    const int rowBlocks = (N + 7) / 8;
    const int nodeBlocks = (N + 3) / 4;
    const int finalBlocks = (N + 63) / 64;

    // CSR build (graph shared by both layers)
    hipMemsetAsync(deg, 0, 2 * (size_t)N * sizeof(int), stream);
    hist_kernel<<<edgeBlocks, 256, 0, stream>>>(dst, deg, E);
    scan_partial<<<NB, 256, 0, stream>>>(deg, bsum, N);
    scan_bsum<<<1, 1024, 0, stream>>>(bsum, NB, rowptr, N, E);
    scan_final<<<NB, 256, 0, stream>>>(deg, bsum, rowptr, N);
    fill_kernel<<<edgeBlocks, 256, 0, stream>>>(src, dst, rowptr, cur, csr_src, E);

    // layer 1
    gemm1_kernel<<<rowBlocks, 128, 0, stream>>>(x, W1, a1s, a1d, h_a, es1, ed1, N);
    gather1_kernel<<<nodeBlocks, 256, 0, stream>>>(rowptr, csr_src, es1, ed1, h_a, b1, h1, N);
    // layer 2
    gemm2_kernel<<<rowBlocks, 128, 0, stream>>>(h1, W2, a2s, a2d, h_a, es2, ed2, N);
    gather2_kernel<<<nodeBlocks, 256, 0, stream>>>(rowptr, csr_src, es2, ed2, h_a, b2, h2n, N);
    // final fused concat-GEMM (tiled)
    final_kernel<<<finalBlocks, 256, 0, stream>>>(x, h1, h2n, Wj, bj, out, N);
}